// Round 11
// baseline (475.839 us; speedup 1.0000x reference)
//
#include <hip/hip_runtime.h>
#include <hip/hip_bf16.h>

typedef unsigned int uint;
typedef _Float16 half2_t __attribute__((ext_vector_type(2)));
typedef _Float16 half8 __attribute__((ext_vector_type(8)));
typedef float f32x4 __attribute__((ext_vector_type(4)));

union H2U { uint u; half2_t h; };
union U4H8 { uint4 u; half8 h; };

// sizes: B=64, W=128, K=64, KS=7, EF=128, ET=128, H=256, FH=256
// ws layout (float offsets)
#define OFF_Y    0u           // 64*128*64   = 524288
#define OFF_Z    524288u      // 64*128*192  = 1572864
#define OFF_GI   2097152u     // 64*128*768  = 6291456
#define OFF_WHH  8388608u     // 98304 uints (fp16x2 packed whh, MFMA B-frag layout)
#define OFF_C12  8486912u     // 256
#define OFF_DD   8487168u     // 2
#define OFF_HEND 8487424u     // 64*256 = 16384

// ---------------- pack whh -> MFMA B-fragment layout (all-register, 256-thr gru) --------
// gru thread tid (0..255): wave w=tid>>6, lane l=tid&63. Wave owns n-tiles u=0..11
// (whh rows w*192+u*16 .. +15). Frag (u,q), lane l, pair p holds whh[row][colb(,+1)]:
//   row  = w*192 + u*16 + (l&15)       (= n)
//   colb = q*32 + (l>>4)*8 + 2p        (= k)
// w16[tid*384 + u*32 + q*4 + p]  (98304 uints total)
__global__ __launch_bounds__(256) void k_pack_prep(const float* __restrict__ whh, uint* __restrict__ w16,
                                                   const float* __restrict__ flw, const float* __restrict__ flb,
                                                   const float* __restrict__ fa, float* __restrict__ c12,
                                                   float* __restrict__ dd) {
    __shared__ float red[256];
    int bx = blockIdx.x, tid = threadIdx.x;
    if (bx < 384) {
        int idx = bx * 256 + tid;           // 0..98303
        int tidq = idx / 384;               // gru thread 0..255
        int rem = idx - tidq * 384;
        int u = rem >> 5;                   // 0..11 n-tile
        int q = (rem >> 2) & 7;             // 0..7 k-chunk
        int p = rem & 3;                    // 0..3 pair
        int w = tidq >> 6, l = tidq & 63;
        int row = w * 192 + u * 16 + (l & 15);
        int colb = q * 32 + (l >> 4) * 8 + 2 * p;
        float a = whh[(size_t)row * 256 + colb];
        float b = whh[(size_t)row * 256 + colb + 1];
        H2U uu; uu.h.x = (_Float16)a; uu.h.y = (_Float16)b;
        w16[idx] = uu.u;
    } else {
        if (tid < 128) {
            float a = 0.f, b = 0.f;
            for (int e = 0; e < 128; ++e) {
                float w = flw[e * 128 + tid];
                a = fmaf(w, fa[e], a);
                b = fmaf(w, fa[128 + e], b);
            }
            c12[tid] = a;
            c12[128 + tid] = b;
        }
        int e = tid & 127;
        red[tid] = (tid < 128) ? flb[e] * fa[e] : flb[e] * fa[128 + e];
        __syncthreads();
        if (tid < 2) {
            float s = 0.f;
            for (int q = 0; q < 128; ++q) s += red[tid * 128 + q];
            dd[tid] = s;
        }
    }
}

// ---------------- conv1d (pad 3) + relu -> y and z[:,:,0:64] ----------------
__global__ __launch_bounds__(256) void k_conv(const float* __restrict__ x, const float* __restrict__ cw,
                                              const float* __restrict__ cb, float* __restrict__ y,
                                              float* __restrict__ z) {
    __shared__ float xT[64][41];
    __shared__ float cwL[64 * 64 * 7];
    int b = blockIdx.y, w0 = blockIdx.x * 32, tid = threadIdx.x;
    for (int idx = tid; idx < 38 * 64; idx += 256) {
        int wl = idx / 64, k = idx % 64;
        int wg = w0 - 3 + wl;
        xT[k][wl] = (wg >= 0 && wg < 128) ? x[((size_t)b * 128 + wg) * 64 + k] : 0.f;
    }
    for (int idx = tid; idx < 64 * 64 * 7; idx += 256) cwL[idx] = cw[idx];
    __syncthreads();
    int w_l = tid % 32, kog = tid / 32;
    float acc[8];
#pragma unroll
    for (int i = 0; i < 8; ++i) acc[i] = 0.f;
    for (int ki = 0; ki < 64; ++ki) {
        float x7[7];
#pragma unroll
        for (int u = 0; u < 7; ++u) x7[u] = xT[ki][w_l + u];
#pragma unroll
        for (int koi = 0; koi < 8; ++koi) {
            const float* wp = &cwL[((kog * 8 + koi) * 64 + ki) * 7];
#pragma unroll
            for (int u = 0; u < 7; ++u) acc[koi] = fmaf(x7[u], wp[u], acc[koi]);
        }
    }
    int w = w0 + w_l;
#pragma unroll
    for (int koi = 0; koi < 8; ++koi) {
        int ko = kog * 8 + koi;
        float v = acc[koi] + cb[ko];
        v = v > 0.f ? v : 0.f;
        y[((size_t)b * 128 + w) * 64 + ko] = v;
        z[((size_t)b * 128 + w) * 192 + ko] = v;
    }
}

// ---------------- feature attention -> z[:,:,64:128] ----------------
__global__ __launch_bounds__(256) void k_feat(const float* __restrict__ y, const float* __restrict__ c12,
                                              const float* __restrict__ dd, const float* __restrict__ fb,
                                              float* __restrict__ z) {
    int b = blockIdx.y, w0 = blockIdx.x * 32, tid = threadIdx.x;
    __shared__ float s1L[64], s2L[64];
    __shared__ float attL[64][65];
    __shared__ float yL[32][64];
    __shared__ float cL[256];
    cL[tid] = c12[tid];
    for (int idx = tid; idx < 32 * 64; idx += 256) {
        int wl = idx / 64, j = idx % 64;
        yL[wl][j] = y[((size_t)b * 128 + w0 + wl) * 64 + j];
    }
    __syncthreads();
    if (tid < 128) {
        int k = tid % 64;
        const float* c = (tid < 64) ? cL : cL + 128;
        float acc = 0.f;
        for (int w = 0; w < 128; ++w) acc = fmaf(y[((size_t)b * 128 + w) * 64 + k], c[w], acc);
        if (tid < 64) s1L[k] = acc + dd[0]; else s2L[k] = acc + dd[1];
    }
    __syncthreads();
    if (tid < 64) {
        int k = tid;
        float s1 = s1L[k];
        float m = -1e30f;
        for (int j = 0; j < 64; ++j) {
            float v = s1 + s2L[j];
            float l = fmaxf(v, 0.2f * v);
            float e = l + fb[k * 64 + j];
            attL[k][j] = e;
            m = fmaxf(m, e);
        }
        float s = 0.f;
        for (int j = 0; j < 64; ++j) { float e = __expf(attL[k][j] - m); attL[k][j] = e; s += e; }
        float inv = 1.f / s;
        for (int j = 0; j < 64; ++j) attL[k][j] *= inv;
    }
    __syncthreads();
    int k_l = tid % 64, wg = tid / 64;
    for (int wi = 0; wi < 8; ++wi) {
        int wl = wg * 8 + wi;
        float acc = 0.f;
#pragma unroll 16
        for (int j = 0; j < 64; ++j) acc = fmaf(attL[k_l][j], yL[wl][j], acc);
        float hv = 1.f / (1.f + __expf(-acc));
        z[((size_t)b * 128 + w0 + wl) * 192 + 64 + k_l] = hv;
    }
}

// ---------------- temporal attention -> z[:,:,128:192] (512 threads) ----------------
__global__ __launch_bounds__(512) void k_temp(const float* __restrict__ y, const float* __restrict__ tlw,
                                              const float* __restrict__ tlb, const float* __restrict__ ta,
                                              const float* __restrict__ tbias, float* __restrict__ z) {
    int b = blockIdx.y, i0 = blockIdx.x * 32, tid = threadIdx.x;
    __shared__ __align__(16) float yT[64][132];
    __shared__ __align__(16) float qL[128][128];
    __shared__ __align__(16) float pL[32][128];
    __shared__ __align__(16) float etL[32][128];
    __shared__ __align__(16) float taL[128];
    __shared__ float mred[32][8], sred[32][8];
    __shared__ float mrow[32], invL[32];
    if (tid < 128) taL[tid] = ta[tid];
    for (int idx = tid; idx < 8192; idx += 512) {
        int j = idx >> 6, k = idx & 63;
        yT[k][j] = y[((size_t)b * 128 + j) * 64 + k];
    }
    __syncthreads();
    {
        int c = tid & 127, ih = tid >> 7;
        float w1r[64];
        const float4* w1p = (const float4*)(tlw + c * 128);
#pragma unroll
        for (int q4 = 0; q4 < 16; ++q4) {
            float4 v = w1p[q4];
            w1r[4 * q4] = v.x; w1r[4 * q4 + 1] = v.y; w1r[4 * q4 + 2] = v.z; w1r[4 * q4 + 3] = v.w;
        }
        float base = tlb[c];
#pragma unroll
        for (int ilb = 0; ilb < 2; ++ilb) {
            int j0 = i0 + ih * 8 + ilb * 4;
            float4 acc = {base, base, base, base};
            for (int k = 0; k < 64; ++k) {
                float4 yv = *((const float4*)&yT[k][j0]);
                float w = w1r[k];
                acc.x = fmaf(yv.x, w, acc.x); acc.y = fmaf(yv.y, w, acc.y);
                acc.z = fmaf(yv.z, w, acc.z); acc.w = fmaf(yv.w, w, acc.w);
            }
            int il = ih * 8 + ilb * 4;
            pL[il][c] = acc.x; pL[il + 1][c] = acc.y; pL[il + 2][c] = acc.z; pL[il + 3][c] = acc.w;
        }
    }
    {
        int j = tid & 127, ch = tid >> 7;
        float yreg[64];
#pragma unroll
        for (int k = 0; k < 64; ++k) yreg[k] = yT[k][j];
        for (int cc = 0; cc < 32; ++cc) {
            int c = __builtin_amdgcn_readfirstlane(ch * 32 + cc);
            const float* w2 = tlw + c * 128 + 64;
            float acc = 0.f;
#pragma unroll
            for (int k = 0; k < 64; ++k) acc = fmaf(yreg[k], w2[k], acc);
            qL[c][j] = acc;
        }
    }
    __syncthreads();
    {
        int jg = tid & 31, ih = tid >> 5;
        int j0 = jg * 4;
        int il0 = ih * 2;
        float4 acc0 = *((const float4*)(tbias + (size_t)(i0 + il0) * 128 + j0));
        float4 acc1 = *((const float4*)(tbias + (size_t)(i0 + il0 + 1) * 128 + j0));
        for (int c0 = 0; c0 < 128; c0 += 4) {
            float4 ta4 = *((const float4*)&taL[c0]);
            float4 p0 = *((const float4*)&pL[il0][c0]);
            float4 p1 = *((const float4*)&pL[il0 + 1][c0]);
            float4 q0 = *((const float4*)&qL[c0 + 0][j0]);
            float4 q1 = *((const float4*)&qL[c0 + 1][j0]);
            float4 q2 = *((const float4*)&qL[c0 + 2][j0]);
            float4 q3 = *((const float4*)&qL[c0 + 3][j0]);
#define ETSTEP(qv, tac, pa, pb) { \
            float u; \
            u = (pa) + qv.x; acc0.x = fmaf(fmaxf(u, 0.2f * u), (tac), acc0.x); \
            u = (pa) + qv.y; acc0.y = fmaf(fmaxf(u, 0.2f * u), (tac), acc0.y); \
            u = (pa) + qv.z; acc0.z = fmaf(fmaxf(u, 0.2f * u), (tac), acc0.z); \
            u = (pa) + qv.w; acc0.w = fmaf(fmaxf(u, 0.2f * u), (tac), acc0.w); \
            u = (pb) + qv.x; acc1.x = fmaf(fmaxf(u, 0.2f * u), (tac), acc1.x); \
            u = (pb) + qv.y; acc1.y = fmaf(fmaxf(u, 0.2f * u), (tac), acc1.y); \
            u = (pb) + qv.z; acc1.z = fmaf(fmaxf(u, 0.2f * u), (tac), acc1.z); \
            u = (pb) + qv.w; acc1.w = fmaf(fmaxf(u, 0.2f * u), (tac), acc1.w); }
            ETSTEP(q0, ta4.x, p0.x, p1.x)
            ETSTEP(q1, ta4.y, p0.y, p1.y)
            ETSTEP(q2, ta4.z, p0.z, p1.z)
            ETSTEP(q3, ta4.w, p0.w, p1.w)
#undef ETSTEP
        }
        *((float4*)&etL[il0][j0]) = acc0;
        *((float4*)&etL[il0 + 1][j0]) = acc1;
    }
    __syncthreads();
    if (tid < 256) {
        int il = tid >> 3, seg = tid & 7;
        const float4* ep = (const float4*)&etL[il][seg * 16];
        float m = -1e30f;
#pragma unroll
        for (int q = 0; q < 4; ++q) {
            float4 e = ep[q];
            m = fmaxf(m, fmaxf(fmaxf(e.x, e.y), fmaxf(e.z, e.w)));
        }
        mred[il][seg] = m;
    }
    __syncthreads();
    if (tid < 32) {
        float m = mred[tid][0];
#pragma unroll
        for (int s = 1; s < 8; ++s) m = fmaxf(m, mred[tid][s]);
        mrow[tid] = m;
    }
    __syncthreads();
    if (tid < 256) {
        int il = tid >> 3, seg = tid & 7;
        float m = mrow[il];
        float4* ep = (float4*)&etL[il][seg * 16];
        float s = 0.f;
#pragma unroll
        for (int q = 0; q < 4; ++q) {
            float4 e = ep[q];
            e.x = __expf(e.x - m); e.y = __expf(e.y - m);
            e.z = __expf(e.z - m); e.w = __expf(e.w - m);
            s += (e.x + e.y) + (e.z + e.w);
            ep[q] = e;
        }
        sred[il][seg] = s;
    }
    __syncthreads();
    if (tid < 32) {
        float s = 0.f;
#pragma unroll
        for (int q = 0; q < 8; ++q) s += sred[tid][q];
        invL[tid] = 1.f / s;
    }
    __syncthreads();
    {
        int k = tid & 63, ig = tid >> 6;
        float acc[4] = {0.f, 0.f, 0.f, 0.f};
        const float* yb = y + (size_t)b * 128 * 64 + k;
        for (int j0 = 0; j0 < 128; j0 += 4) {
            float yv[4];
#pragma unroll
            for (int jj = 0; jj < 4; ++jj) yv[jj] = yb[(size_t)(j0 + jj) * 64];
#pragma unroll
            for (int ii = 0; ii < 4; ++ii) {
                int il = ig * 4 + ii;
                float4 ev = *((const float4*)&etL[il][j0]);
                acc[ii] = fmaf(ev.x, yv[0], acc[ii]);
                acc[ii] = fmaf(ev.y, yv[1], acc[ii]);
                acc[ii] = fmaf(ev.z, yv[2], acc[ii]);
                acc[ii] = fmaf(ev.w, yv[3], acc[ii]);
            }
        }
#pragma unroll
        for (int ii = 0; ii < 4; ++ii) {
            int il = ig * 4 + ii;
            float hv = 1.f / (1.f + __expf(-acc[ii] * invL[il]));
            z[((size_t)b * 128 + i0 + il) * 192 + 128 + k] = hv;
        }
    }
}

// ---------------- gi = z @ wih.T + bih : (8192,192)@(192,768), register-blocked ----------------
__global__ __launch_bounds__(256) void k_gi(const float* __restrict__ z, const float* __restrict__ wih,
                                            const float* __restrict__ bih, float* __restrict__ gi) {
    int o0 = blockIdx.x * 128;
    int bt0 = blockIdx.y * 64;
    int tid = threadIdx.x;
    __shared__ __align__(16) float zL[64][68];
    __shared__ float wL[128][65];
    int ol = tid & 31;
    int r8 = (tid >> 5) * 8;
    float acc[8][4];
#pragma unroll
    for (int rr = 0; rr < 8; ++rr)
#pragma unroll
        for (int oo = 0; oo < 4; ++oo) acc[rr][oo] = 0.f;
    for (int mc = 0; mc < 3; ++mc) {
        int m0 = mc * 64;
        __syncthreads();
        {
            int mq = (tid & 15) * 4;
            int r = tid >> 4;
#pragma unroll
            for (int it = 0; it < 4; ++it, r += 16) {
                float4 v = *((const float4*)&z[(size_t)(bt0 + r) * 192 + m0 + mq]);
                *((float4*)&zL[r][mq]) = v;
            }
            int o = tid >> 4;
#pragma unroll
            for (int it = 0; it < 8; ++it, o += 16) {
                float4 v = *((const float4*)&wih[(size_t)(o0 + o) * 192 + m0 + mq]);
                wL[o][mq] = v.x; wL[o][mq + 1] = v.y; wL[o][mq + 2] = v.z; wL[o][mq + 3] = v.w;
            }
        }
        __syncthreads();
        for (int mb = 0; mb < 64; mb += 4) {
            float4 zv[8];
#pragma unroll
            for (int rr = 0; rr < 8; ++rr) zv[rr] = *((const float4*)&zL[r8 + rr][mb]);
#pragma unroll
            for (int mi = 0; mi < 4; ++mi) {
                float wv[4];
#pragma unroll
                for (int oo = 0; oo < 4; ++oo) wv[oo] = wL[ol + 32 * oo][mb + mi];
#pragma unroll
                for (int rr = 0; rr < 8; ++rr) {
                    float zc = (mi == 0) ? zv[rr].x : (mi == 1) ? zv[rr].y : (mi == 2) ? zv[rr].z : zv[rr].w;
#pragma unroll
                    for (int oo = 0; oo < 4; ++oo) acc[rr][oo] = fmaf(zc, wv[oo], acc[rr][oo]);
                }
            }
        }
    }
    float bo[4];
#pragma unroll
    for (int oo = 0; oo < 4; ++oo) bo[oo] = bih[o0 + ol + 32 * oo];
#pragma unroll
    for (int rr = 0; rr < 8; ++rr)
#pragma unroll
        for (int oo = 0; oo < 4; ++oo)
            gi[(size_t)(bt0 + r8 + rr) * 768 + o0 + ol + 32 * oo] = acc[rr][oo] + bo[oo];
}

// ---------------- GRU via MFMA, all-register weights: 64 blocks, 256 thr (4 waves) -------
// 1 wave/SIMD (waves_per_eu(1,1)) -> 512-reg unified budget/thread (the m08/m24 no-spill
// regime). Each wave owns 12 n-tiles: 96 B-frags = 384 regs + 48 acc + ~40 arch ~= 480 < 512.
// Zero per-step weight traffic; per-step LDS = 8 A-broadcast b128/wave + 12 sH b32 writes.
__global__ __launch_bounds__(256)
__attribute__((amdgpu_waves_per_eu(1, 1)))
void k_gru(const float* __restrict__ gi,
           const uint* __restrict__ w16,
           const float* __restrict__ bhh,
           float* __restrict__ hend) {
    int b = blockIdx.x, tid = threadIdx.x;
    int w = tid >> 6, l = tid & 63;
    int quad = l >> 4;
    __shared__ __align__(16) _Float16 hp16[256];
    __shared__ float sH[768];
    half8 bfr[96];   // [u*8+q], u=0..11 — constant-indexed, SROA -> 96 SSA half8 (384 regs)
    {
        const uint4* wp4 = (const uint4*)(w16 + (size_t)tid * 384);
#pragma unroll
        for (int i = 0; i < 96; ++i) { U4H8 c_; c_.u = wp4[i]; bfr[i] = c_.h; }
    }
    float br = bhh[tid], bz = bhh[256 + tid], bn = bhh[512 + tid];
    float h = 0.f;
    if (tid < 128) ((uint*)hp16)[tid] = 0u;
    __syncthreads();
    const float* gib = gi + (size_t)b * 128 * 768;
    const uint4* hp4 = (const uint4*)hp16;
    for (int s = 0; s < 128; ++s) {
        float gr = gib[s * 768 + tid];
        float gz = gib[s * 768 + 256 + tid];
        float gn = gib[s * 768 + 512 + tid];
        f32x4 acc[12];
#pragma unroll
        for (int u = 0; u < 12; ++u) acc[u] = (f32x4){0.f, 0.f, 0.f, 0.f};
#pragma unroll
        for (int q = 0; q < 8; ++q) {
            U4H8 c_; c_.u = hp4[q * 4 + quad];   // broadcast: h[q*32+quad*8 .. +8)
            half8 av = c_.h;
#pragma unroll
            for (int u = 0; u < 12; ++u)
                acc[u] = __builtin_amdgcn_mfma_f32_16x16x32_f16(av, bfr[u * 8 + q], acc[u], 0, 0, 0);
        }
        if (l < 16) {  // C/D: col=lane&15, row=(lane>>4)*4+reg -> row 0 = lanes 0..15, reg 0
            int base = w * 192 + l;
#pragma unroll
            for (int u = 0; u < 12; ++u) sH[base + u * 16] = acc[u][0];
        }
        __syncthreads();
        {
            float hr = sH[tid] + br;
            float hz = sH[256 + tid] + bz;
            float hn = sH[512 + tid] + bn;
            float r  = 1.f / (1.f + __expf(-(gr + hr)));
            float zg = 1.f / (1.f + __expf(-(gz + hz)));
            float nx = gn + r * hn;
            float n  = 1.f - 2.f / (1.f + __expf(2.f * nx)); // tanh
            h = (1.f - zg) * n + zg * h;
            hp16[tid] = (_Float16)h;
        }
        __syncthreads();
    }
    hend[b * 256 + tid] = h;
}

// ---------------- FC head ----------------
__global__ __launch_bounds__(256) void k_fc(const float* __restrict__ hend,
                                            const float* __restrict__ w0, const float* __restrict__ b0,
                                            const float* __restrict__ w1, const float* __restrict__ b1,
                                            const float* __restrict__ w2, const float* __restrict__ b2,
                                            const float* __restrict__ w3, const float* __restrict__ b3,
                                            float* __restrict__ out) {
    int b = blockIdx.x, tid = threadIdx.x;
    __shared__ float bufA[256], bufB[256];
    bufA[tid] = hend[b * 256 + tid];
    __syncthreads();
    {
        float acc = b0[tid];
        const float* wrow = &w0[tid * 256];
#pragma unroll 8
        for (int m = 0; m < 256; ++m) acc = fmaf(wrow[m], bufA[m], acc);
        bufB[tid] = fmaxf(acc, 0.f);
    }
    __syncthreads();
    {
        float acc = b1[tid];
        const float* wrow = &w1[tid * 256];
#pragma unroll 8
        for (int m = 0; m < 256; ++m) acc = fmaf(wrow[m], bufB[m], acc);
        bufA[tid] = fmaxf(acc, 0.f);
    }
    __syncthreads();
    {
        float acc = b2[tid];
        const float* wrow = &w2[tid * 256];
#pragma unroll 8
        for (int m = 0; m < 256; ++m) acc = fmaf(wrow[m], bufA[m], acc);
        bufB[tid] = fmaxf(acc, 0.f);
    }
    __syncthreads();
    if (tid < 64) {
        float acc = b3[tid];
        const float* wrow = &w3[tid * 256];
#pragma unroll 8
        for (int m = 0; m < 256; ++m) acc = fmaf(wrow[m], bufB[m], acc);
        out[b * 64 + tid] = acc;
    }
}

extern "C" void kernel_launch(void* const* d_in, const int* in_sizes, int n_in,
                              void* d_out, int out_size, void* d_ws, size_t ws_size,
                              hipStream_t stream) {
    const float* x    = (const float*)d_in[0];
    const float* cw   = (const float*)d_in[1];
    const float* cb   = (const float*)d_in[2];
    const float* flw  = (const float*)d_in[3];
    const float* flb  = (const float*)d_in[4];
    const float* fa   = (const float*)d_in[5];
    const float* fb   = (const float*)d_in[6];
    const float* tlw  = (const float*)d_in[7];
    const float* tlb  = (const float*)d_in[8];
    const float* ta   = (const float*)d_in[9];
    const float* tb   = (const float*)d_in[10];
    const float* wih  = (const float*)d_in[11];
    const float* whh  = (const float*)d_in[12];
    const float* bih  = (const float*)d_in[13];
    const float* bhh  = (const float*)d_in[14];
    const float* fc0w = (const float*)d_in[15];
    const float* fc0b = (const float*)d_in[16];
    const float* fc1w = (const float*)d_in[17];
    const float* fc1b = (const float*)d_in[18];
    const float* fc2w = (const float*)d_in[19];
    const float* fc2b = (const float*)d_in[20];
    const float* fc3w = (const float*)d_in[21];
    const float* fc3b = (const float*)d_in[22];

    float* wsf  = (float*)d_ws;
    float* y    = wsf + OFF_Y;
    float* z    = wsf + OFF_Z;
    float* gi   = wsf + OFF_GI;
    uint*  w16  = (uint*)(wsf + OFF_WHH);
    float* c12  = wsf + OFF_C12;
    float* dd   = wsf + OFF_DD;
    float* hend = wsf + OFF_HEND;
    float* out  = (float*)d_out;

    k_pack_prep<<<385, 256, 0, stream>>>(whh, w16, flw, flb, fa, c12, dd);
    k_conv<<<dim3(4, 64), 256, 0, stream>>>(x, cw, cb, y, z);
    k_feat<<<dim3(4, 64), 256, 0, stream>>>(y, c12, dd, fb, z);
    k_temp<<<dim3(4, 64), 512, 0, stream>>>(y, tlw, tlb, ta, tb, z);
    k_gi<<<dim3(6, 128), 256, 0, stream>>>(z, wih, bih, gi);
    k_gru<<<64, 256, 0, stream>>>(gi, w16, bhh, hend);
    k_fc<<<64, 256, 0, stream>>>(hend, fc0w, fc0b, fc1w, fc1b, fc2w, fc2b, fc3w, fc3b, out);
}

// Round 12
// 399.440 us; speedup vs baseline: 1.1913x; 1.1913x over previous
//
#include <hip/hip_runtime.h>
#include <hip/hip_bf16.h>

typedef unsigned int uint;
typedef _Float16 half2_t __attribute__((ext_vector_type(2)));
typedef _Float16 half8 __attribute__((ext_vector_type(8)));
typedef float f32x4 __attribute__((ext_vector_type(4)));

union H2U { uint u; half2_t h; };
union U4H8 { uint4 u; half8 h; };

// sizes: B=64, W=128, K=64, KS=7, EF=128, ET=128, H=256, FH=256
// ws layout (float offsets)
#define OFF_Y    0u           // 64*128*64   = 524288
#define OFF_Z    524288u      // 64*128*192  = 1572864
#define OFF_GI   2097152u     // 64*128*768  = 6291456
#define OFF_WHH  8388608u     // 98304 uints (fp16x2 packed whh, MFMA B-frag layout)
#define OFF_C12  8486912u     // 256
#define OFF_DD   8487168u     // 2
#define OFF_HEND 8487424u     // 64*256 = 16384

// ---------------- pack whh -> MFMA B-fragment layout (r9 convention, verified) ----------
// gru thread tid (0..511): wave w=tid>>6, lane l=tid&63. Wave owns n-tiles u=0..5
// (whh rows w*96+u*16 .. +15). Frag (u,q): lane l, pair p holds whh[row][colb(,+1)]:
//   row = w*96 + u*16 + (l&15), colb = q*32 + (l>>4)*8 + 2p.  w16[tid*192 + u*32 + q*4 + p]
__global__ __launch_bounds__(256) void k_pack_prep(const float* __restrict__ whh, uint* __restrict__ w16,
                                                   const float* __restrict__ flw, const float* __restrict__ flb,
                                                   const float* __restrict__ fa, float* __restrict__ c12,
                                                   float* __restrict__ dd) {
    __shared__ float red[256];
    int bx = blockIdx.x, tid = threadIdx.x;
    if (bx < 384) {
        int idx = bx * 256 + tid;           // 0..98303
        int tidq = idx / 192;               // gru thread 0..511
        int r = idx - tidq * 192;
        int u = r >> 5;                     // 0..5 n-tile
        int q = (r >> 2) & 7;               // 0..7 k-chunk
        int p = r & 3;                      // 0..3 pair
        int w = tidq >> 6;
        int l = tidq & 63;
        int row = w * 96 + u * 16 + (l & 15);          // whh row (= n)
        int colb = q * 32 + (l >> 4) * 8 + 2 * p;      // whh col (= k)
        float a = whh[(size_t)row * 256 + colb];
        float b = whh[(size_t)row * 256 + colb + 1];
        H2U uu; uu.h.x = (_Float16)a; uu.h.y = (_Float16)b;
        w16[idx] = uu.u;
    } else {
        if (tid < 128) {
            float a = 0.f, b = 0.f;
            for (int e = 0; e < 128; ++e) {
                float w = flw[e * 128 + tid];
                a = fmaf(w, fa[e], a);
                b = fmaf(w, fa[128 + e], b);
            }
            c12[tid] = a;
            c12[128 + tid] = b;
        }
        int e = tid & 127;
        red[tid] = (tid < 128) ? flb[e] * fa[e] : flb[e] * fa[128 + e];
        __syncthreads();
        if (tid < 2) {
            float s = 0.f;
            for (int q = 0; q < 128; ++q) s += red[tid * 128 + q];
            dd[tid] = s;
        }
    }
}

// ---------------- conv1d (pad 3) + relu -> y and z[:,:,0:64] ----------------
__global__ __launch_bounds__(256) void k_conv(const float* __restrict__ x, const float* __restrict__ cw,
                                              const float* __restrict__ cb, float* __restrict__ y,
                                              float* __restrict__ z) {
    __shared__ float xT[64][41];
    __shared__ float cwL[64 * 64 * 7];
    int b = blockIdx.y, w0 = blockIdx.x * 32, tid = threadIdx.x;
    for (int idx = tid; idx < 38 * 64; idx += 256) {
        int wl = idx / 64, k = idx % 64;
        int wg = w0 - 3 + wl;
        xT[k][wl] = (wg >= 0 && wg < 128) ? x[((size_t)b * 128 + wg) * 64 + k] : 0.f;
    }
    for (int idx = tid; idx < 64 * 64 * 7; idx += 256) cwL[idx] = cw[idx];
    __syncthreads();
    int w_l = tid % 32, kog = tid / 32;
    float acc[8];
#pragma unroll
    for (int i = 0; i < 8; ++i) acc[i] = 0.f;
    for (int ki = 0; ki < 64; ++ki) {
        float x7[7];
#pragma unroll
        for (int u = 0; u < 7; ++u) x7[u] = xT[ki][w_l + u];
#pragma unroll
        for (int koi = 0; koi < 8; ++koi) {
            const float* wp = &cwL[((kog * 8 + koi) * 64 + ki) * 7];
#pragma unroll
            for (int u = 0; u < 7; ++u) acc[koi] = fmaf(x7[u], wp[u], acc[koi]);
        }
    }
    int w = w0 + w_l;
#pragma unroll
    for (int koi = 0; koi < 8; ++koi) {
        int ko = kog * 8 + koi;
        float v = acc[koi] + cb[ko];
        v = v > 0.f ? v : 0.f;
        y[((size_t)b * 128 + w) * 64 + ko] = v;
        z[((size_t)b * 128 + w) * 192 + ko] = v;
    }
}

// ---------------- feature attention -> z[:,:,64:128] ----------------
__global__ __launch_bounds__(256) void k_feat(const float* __restrict__ y, const float* __restrict__ c12,
                                              const float* __restrict__ dd, const float* __restrict__ fb,
                                              float* __restrict__ z) {
    int b = blockIdx.y, w0 = blockIdx.x * 32, tid = threadIdx.x;
    __shared__ float s1L[64], s2L[64];
    __shared__ float attL[64][65];
    __shared__ float yL[32][64];
    __shared__ float cL[256];
    cL[tid] = c12[tid];
    for (int idx = tid; idx < 32 * 64; idx += 256) {
        int wl = idx / 64, j = idx % 64;
        yL[wl][j] = y[((size_t)b * 128 + w0 + wl) * 64 + j];
    }
    __syncthreads();
    if (tid < 128) {
        int k = tid % 64;
        const float* c = (tid < 64) ? cL : cL + 128;
        float acc = 0.f;
        for (int w = 0; w < 128; ++w) acc = fmaf(y[((size_t)b * 128 + w) * 64 + k], c[w], acc);
        if (tid < 64) s1L[k] = acc + dd[0]; else s2L[k] = acc + dd[1];
    }
    __syncthreads();
    if (tid < 64) {
        int k = tid;
        float s1 = s1L[k];
        float m = -1e30f;
        for (int j = 0; j < 64; ++j) {
            float v = s1 + s2L[j];
            float l = fmaxf(v, 0.2f * v);
            float e = l + fb[k * 64 + j];
            attL[k][j] = e;
            m = fmaxf(m, e);
        }
        float s = 0.f;
        for (int j = 0; j < 64; ++j) { float e = __expf(attL[k][j] - m); attL[k][j] = e; s += e; }
        float inv = 1.f / s;
        for (int j = 0; j < 64; ++j) attL[k][j] *= inv;
    }
    __syncthreads();
    int k_l = tid % 64, wg = tid / 64;
    for (int wi = 0; wi < 8; ++wi) {
        int wl = wg * 8 + wi;
        float acc = 0.f;
#pragma unroll 16
        for (int j = 0; j < 64; ++j) acc = fmaf(attL[k_l][j], yL[wl][j], acc);
        float hv = 1.f / (1.f + __expf(-acc));
        z[((size_t)b * 128 + w0 + wl) * 192 + 64 + k_l] = hv;
    }
}

// ---------------- temporal attention -> z[:,:,128:192] (512 threads) ----------------
// q-phase rewritten: p-style register blocking (w2 row in VGPRs, broadcast b128 yT reads).
// No readfirstlane / scalar-load tricks. qL padded to stride 132 for c-major b128 stores.
__global__ __launch_bounds__(512) void k_temp(const float* __restrict__ y, const float* __restrict__ tlw,
                                              const float* __restrict__ tlb, const float* __restrict__ ta,
                                              const float* __restrict__ tbias, float* __restrict__ z) {
    int b = blockIdx.y, i0 = blockIdx.x * 32, tid = threadIdx.x;
    __shared__ __align__(16) float yT[64][132];
    __shared__ __align__(16) float qL[128][132];
    __shared__ __align__(16) float pL[32][128];
    __shared__ __align__(16) float etL[32][128];
    __shared__ __align__(16) float taL[128];
    __shared__ float mred[32][8], sred[32][8];
    __shared__ float mrow[32], invL[32];
    if (tid < 128) taL[tid] = ta[tid];
    for (int idx = tid; idx < 8192; idx += 512) {
        int j = idx >> 6, k = idx & 63;
        yT[k][j] = y[((size_t)b * 128 + j) * 64 + k];
    }
    __syncthreads();
    {   // ---- p = y_slice @ W1^T + tlb -> pL[il][c] ----
        int c = tid & 127, ih = tid >> 7;
        float w1r[64];
        const float4* w1p = (const float4*)(tlw + c * 128);
#pragma unroll
        for (int q4 = 0; q4 < 16; ++q4) {
            float4 v = w1p[q4];
            w1r[4 * q4] = v.x; w1r[4 * q4 + 1] = v.y; w1r[4 * q4 + 2] = v.z; w1r[4 * q4 + 3] = v.w;
        }
        float base = tlb[c];
#pragma unroll
        for (int ilb = 0; ilb < 2; ++ilb) {
            int j0 = i0 + ih * 8 + ilb * 4;
            float4 acc = {base, base, base, base};
            for (int k = 0; k < 64; ++k) {
                float4 yv = *((const float4*)&yT[k][j0]);
                float w = w1r[k];
                acc.x = fmaf(yv.x, w, acc.x); acc.y = fmaf(yv.y, w, acc.y);
                acc.z = fmaf(yv.z, w, acc.z); acc.w = fmaf(yv.w, w, acc.w);
            }
            int il = ih * 8 + ilb * 4;
            pL[il][c] = acc.x; pL[il + 1][c] = acc.y; pL[il + 2][c] = acc.z; pL[il + 3][c] = acc.w;
        }
    }
    {   // ---- q = y @ W2^T -> qL[c][j], thread (c, ih) covers j = ih*32 .. +31 ----
        int c = tid & 127, ih = tid >> 7;
        float w2r[64];
        const float4* w2p = (const float4*)(tlw + c * 128 + 64);
#pragma unroll
        for (int q4 = 0; q4 < 16; ++q4) {
            float4 v = w2p[q4];
            w2r[4 * q4] = v.x; w2r[4 * q4 + 1] = v.y; w2r[4 * q4 + 2] = v.z; w2r[4 * q4 + 3] = v.w;
        }
#pragma unroll
        for (int jq = 0; jq < 8; ++jq) {
            int j0 = ih * 32 + jq * 4;
            float4 acc = {0.f, 0.f, 0.f, 0.f};
            for (int k = 0; k < 64; ++k) {
                float4 yv = *((const float4*)&yT[k][j0]);
                float w = w2r[k];
                acc.x = fmaf(yv.x, w, acc.x); acc.y = fmaf(yv.y, w, acc.y);
                acc.z = fmaf(yv.z, w, acc.z); acc.w = fmaf(yv.w, w, acc.w);
            }
            *((float4*)&qL[c][j0]) = acc;
        }
    }
    __syncthreads();
    {   // ---- e_t[il][j] = sum_c leaky(p+q)*ta + tbias ----
        int jg = tid & 31, ih = tid >> 5;
        int j0 = jg * 4;
        int il0 = ih * 2;
        float4 acc0 = *((const float4*)(tbias + (size_t)(i0 + il0) * 128 + j0));
        float4 acc1 = *((const float4*)(tbias + (size_t)(i0 + il0 + 1) * 128 + j0));
        for (int c0 = 0; c0 < 128; c0 += 4) {
            float4 ta4 = *((const float4*)&taL[c0]);
            float4 p0 = *((const float4*)&pL[il0][c0]);
            float4 p1 = *((const float4*)&pL[il0 + 1][c0]);
            float4 q0 = *((const float4*)&qL[c0 + 0][j0]);
            float4 q1 = *((const float4*)&qL[c0 + 1][j0]);
            float4 q2 = *((const float4*)&qL[c0 + 2][j0]);
            float4 q3 = *((const float4*)&qL[c0 + 3][j0]);
#define ETSTEP(qv, tac, pa, pb) { \
            float u; \
            u = (pa) + qv.x; acc0.x = fmaf(fmaxf(u, 0.2f * u), (tac), acc0.x); \
            u = (pa) + qv.y; acc0.y = fmaf(fmaxf(u, 0.2f * u), (tac), acc0.y); \
            u = (pa) + qv.z; acc0.z = fmaf(fmaxf(u, 0.2f * u), (tac), acc0.z); \
            u = (pa) + qv.w; acc0.w = fmaf(fmaxf(u, 0.2f * u), (tac), acc0.w); \
            u = (pb) + qv.x; acc1.x = fmaf(fmaxf(u, 0.2f * u), (tac), acc1.x); \
            u = (pb) + qv.y; acc1.y = fmaf(fmaxf(u, 0.2f * u), (tac), acc1.y); \
            u = (pb) + qv.z; acc1.z = fmaf(fmaxf(u, 0.2f * u), (tac), acc1.z); \
            u = (pb) + qv.w; acc1.w = fmaf(fmaxf(u, 0.2f * u), (tac), acc1.w); }
            ETSTEP(q0, ta4.x, p0.x, p1.x)
            ETSTEP(q1, ta4.y, p0.y, p1.y)
            ETSTEP(q2, ta4.z, p0.z, p1.z)
            ETSTEP(q3, ta4.w, p0.w, p1.w)
#undef ETSTEP
        }
        *((float4*)&etL[il0][j0]) = acc0;
        *((float4*)&etL[il0 + 1][j0]) = acc1;
    }
    __syncthreads();
    if (tid < 256) {
        int il = tid >> 3, seg = tid & 7;
        const float4* ep = (const float4*)&etL[il][seg * 16];
        float m = -1e30f;
#pragma unroll
        for (int q = 0; q < 4; ++q) {
            float4 e = ep[q];
            m = fmaxf(m, fmaxf(fmaxf(e.x, e.y), fmaxf(e.z, e.w)));
        }
        mred[il][seg] = m;
    }
    __syncthreads();
    if (tid < 32) {
        float m = mred[tid][0];
#pragma unroll
        for (int s = 1; s < 8; ++s) m = fmaxf(m, mred[tid][s]);
        mrow[tid] = m;
    }
    __syncthreads();
    if (tid < 256) {
        int il = tid >> 3, seg = tid & 7;
        float m = mrow[il];
        float4* ep = (float4*)&etL[il][seg * 16];
        float s = 0.f;
#pragma unroll
        for (int q = 0; q < 4; ++q) {
            float4 e = ep[q];
            e.x = __expf(e.x - m); e.y = __expf(e.y - m);
            e.z = __expf(e.z - m); e.w = __expf(e.w - m);
            s += (e.x + e.y) + (e.z + e.w);
            ep[q] = e;
        }
        sred[il][seg] = s;
    }
    __syncthreads();
    if (tid < 32) {
        float s = 0.f;
#pragma unroll
        for (int q = 0; q < 8; ++q) s += sred[tid][q];
        invL[tid] = 1.f / s;
    }
    __syncthreads();
    {
        int k = tid & 63, ig = tid >> 6;
        float acc[4] = {0.f, 0.f, 0.f, 0.f};
        const float* yb = y + (size_t)b * 128 * 64 + k;
        for (int j0 = 0; j0 < 128; j0 += 4) {
            float yv[4];
#pragma unroll
            for (int jj = 0; jj < 4; ++jj) yv[jj] = yb[(size_t)(j0 + jj) * 64];
#pragma unroll
            for (int ii = 0; ii < 4; ++ii) {
                int il = ig * 4 + ii;
                float4 ev = *((const float4*)&etL[il][j0]);
                acc[ii] = fmaf(ev.x, yv[0], acc[ii]);
                acc[ii] = fmaf(ev.y, yv[1], acc[ii]);
                acc[ii] = fmaf(ev.z, yv[2], acc[ii]);
                acc[ii] = fmaf(ev.w, yv[3], acc[ii]);
            }
        }
#pragma unroll
        for (int ii = 0; ii < 4; ++ii) {
            int il = ig * 4 + ii;
            float hv = 1.f / (1.f + __expf(-acc[ii] * invL[il]));
            z[((size_t)b * 128 + i0 + il) * 192 + 128 + k] = hv;
        }
    }
}

// ---------------- gi = z @ wih.T + bih : (8192,192)@(192,768), register-blocked ----------------
__global__ __launch_bounds__(256) void k_gi(const float* __restrict__ z, const float* __restrict__ wih,
                                            const float* __restrict__ bih, float* __restrict__ gi) {
    int o0 = blockIdx.x * 128;
    int bt0 = blockIdx.y * 64;
    int tid = threadIdx.x;
    __shared__ __align__(16) float zL[64][68];
    __shared__ float wL[128][65];
    int ol = tid & 31;
    int r8 = (tid >> 5) * 8;
    float acc[8][4];
#pragma unroll
    for (int rr = 0; rr < 8; ++rr)
#pragma unroll
        for (int oo = 0; oo < 4; ++oo) acc[rr][oo] = 0.f;
    for (int mc = 0; mc < 3; ++mc) {
        int m0 = mc * 64;
        __syncthreads();
        {
            int mq = (tid & 15) * 4;
            int r = tid >> 4;
#pragma unroll
            for (int it = 0; it < 4; ++it, r += 16) {
                float4 v = *((const float4*)&z[(size_t)(bt0 + r) * 192 + m0 + mq]);
                *((float4*)&zL[r][mq]) = v;
            }
            int o = tid >> 4;
#pragma unroll
            for (int it = 0; it < 8; ++it, o += 16) {
                float4 v = *((const float4*)&wih[(size_t)(o0 + o) * 192 + m0 + mq]);
                wL[o][mq] = v.x; wL[o][mq + 1] = v.y; wL[o][mq + 2] = v.z; wL[o][mq + 3] = v.w;
            }
        }
        __syncthreads();
        for (int mb = 0; mb < 64; mb += 4) {
            float4 zv[8];
#pragma unroll
            for (int rr = 0; rr < 8; ++rr) zv[rr] = *((const float4*)&zL[r8 + rr][mb]);
#pragma unroll
            for (int mi = 0; mi < 4; ++mi) {
                float wv[4];
#pragma unroll
                for (int oo = 0; oo < 4; ++oo) wv[oo] = wL[ol + 32 * oo][mb + mi];
#pragma unroll
                for (int rr = 0; rr < 8; ++rr) {
                    float zc = (mi == 0) ? zv[rr].x : (mi == 1) ? zv[rr].y : (mi == 2) ? zv[rr].z : zv[rr].w;
#pragma unroll
                    for (int oo = 0; oo < 4; ++oo) acc[rr][oo] = fmaf(zc, wv[oo], acc[rr][oo]);
                }
            }
        }
    }
    float bo[4];
#pragma unroll
    for (int oo = 0; oo < 4; ++oo) bo[oo] = bih[o0 + ol + 32 * oo];
#pragma unroll
    for (int rr = 0; rr < 8; ++rr)
#pragma unroll
        for (int oo = 0; oo < 4; ++oo)
            gi[(size_t)(bt0 + r8 + rr) * 768 + o0 + ol + 32 * oo] = acc[rr][oo] + bo[oo];
}

// ---------------- GRU via MFMA (r9 version — best measured: ~151 us) ----------------
__global__ __launch_bounds__(512)
__attribute__((amdgpu_waves_per_eu(2, 2)))
void k_gru(const float* __restrict__ gi,
           const uint* __restrict__ w16,
           const float* __restrict__ bhh,
           float* __restrict__ hend) {
    int b = blockIdx.x, tid = threadIdx.x;
    int w = tid >> 6, l = tid & 63;
    int t = tid & 255;
    int quad = l >> 4;
    __shared__ __align__(16) _Float16 hp16[256];
    __shared__ float sH[768];
    half8 bfr[48];   // [u*8+q] — fully unrolled; SROA -> 48 SSA values (192 regs)
    {
        const uint4* wp4 = (const uint4*)(w16 + (size_t)tid * 192);
#pragma unroll
        for (int i = 0; i < 48; ++i) { U4H8 c_; c_.u = wp4[i]; bfr[i] = c_.h; }
    }
    float br = 0.f, bz = 0.f, bn = 0.f;
    if (tid < 256) { br = bhh[t]; bz = bhh[256 + t]; bn = bhh[512 + t]; }
    float h = 0.f;
    if (tid < 128) ((uint*)hp16)[tid] = 0u;
    __syncthreads();
    const float* gib = gi + (size_t)b * 128 * 768;
    const uint4* hp4 = (const uint4*)hp16;
    for (int s = 0; s < 128; ++s) {
        float gr = 0.f, gz = 0.f, gn = 0.f;
        if (tid < 256) {
            gr = gib[s * 768 + t];
            gz = gib[s * 768 + 256 + t];
            gn = gib[s * 768 + 512 + t];
        }
        f32x4 acc[6];
#pragma unroll
        for (int u = 0; u < 6; ++u) acc[u] = (f32x4){0.f, 0.f, 0.f, 0.f};
#pragma unroll
        for (int q = 0; q < 8; ++q) {
            U4H8 c_; c_.u = hp4[q * 4 + quad];   // broadcast: h[q*32+quad*8 .. +8)
            half8 av = c_.h;
#pragma unroll
            for (int u = 0; u < 6; ++u)
                acc[u] = __builtin_amdgcn_mfma_f32_16x16x32_f16(av, bfr[u * 8 + q], acc[u], 0, 0, 0);
        }
        if (l < 16) {
            int base = w * 96 + l;
            sH[base +  0] = acc[0][0];
            sH[base + 16] = acc[1][0];
            sH[base + 32] = acc[2][0];
            sH[base + 48] = acc[3][0];
            sH[base + 64] = acc[4][0];
            sH[base + 80] = acc[5][0];
        }
        __syncthreads();
        if (tid < 256) {
            float hr = sH[t] + br;
            float hz = sH[256 + t] + bz;
            float hn = sH[512 + t] + bn;
            float r  = 1.f / (1.f + __expf(-(gr + hr)));
            float zg = 1.f / (1.f + __expf(-(gz + hz)));
            float nx = gn + r * hn;
            float n  = 1.f - 2.f / (1.f + __expf(2.f * nx)); // tanh
            h = (1.f - zg) * n + zg * h;
            hp16[t] = (_Float16)h;
        }
        __syncthreads();
    }
    if (tid < 256) hend[b * 256 + t] = h;
}

// ---------------- FC head ----------------
__global__ __launch_bounds__(256) void k_fc(const float* __restrict__ hend,
                                            const float* __restrict__ w0, const float* __restrict__ b0,
                                            const float* __restrict__ w1, const float* __restrict__ b1,
                                            const float* __restrict__ w2, const float* __restrict__ b2,
                                            const float* __restrict__ w3, const float* __restrict__ b3,
                                            float* __restrict__ out) {
    int b = blockIdx.x, tid = threadIdx.x;
    __shared__ float bufA[256], bufB[256];
    bufA[tid] = hend[b * 256 + tid];
    __syncthreads();
    {
        float acc = b0[tid];
        const float* wrow = &w0[tid * 256];
#pragma unroll 8
        for (int m = 0; m < 256; ++m) acc = fmaf(wrow[m], bufA[m], acc);
        bufB[tid] = fmaxf(acc, 0.f);
    }
    __syncthreads();
    {
        float acc = b1[tid];
        const float* wrow = &w1[tid * 256];
#pragma unroll 8
        for (int m = 0; m < 256; ++m) acc = fmaf(wrow[m], bufB[m], acc);
        bufA[tid] = fmaxf(acc, 0.f);
    }
    __syncthreads();
    {
        float acc = b2[tid];
        const float* wrow = &w2[tid * 256];
#pragma unroll 8
        for (int m = 0; m < 256; ++m) acc = fmaf(wrow[m], bufA[m], acc);
        bufB[tid] = fmaxf(acc, 0.f);
    }
    __syncthreads();
    if (tid < 64) {
        float acc = b3[tid];
        const float* wrow = &w3[tid * 256];
#pragma unroll 8
        for (int m = 0; m < 256; ++m) acc = fmaf(wrow[m], bufB[m], acc);
        out[b * 64 + tid] = acc;
    }
}

extern "C" void kernel_launch(void* const* d_in, const int* in_sizes, int n_in,
                              void* d_out, int out_size, void* d_ws, size_t ws_size,
                              hipStream_t stream) {
    const float* x    = (const float*)d_in[0];
    const float* cw   = (const float*)d_in[1];
    const float* cb   = (const float*)d_in[2];
    const float* flw  = (const float*)d_in[3];
    const float* flb  = (const float*)d_in[4];
    const float* fa   = (const float*)d_in[5];
    const float* fb   = (const float*)d_in[6];
    const float* tlw  = (const float*)d_in[7];
    const float* tlb  = (const float*)d_in[8];
    const float* ta   = (const float*)d_in[9];
    const float* tb   = (const float*)d_in[10];
    const float* wih  = (const float*)d_in[11];
    const float* whh  = (const float*)d_in[12];
    const float* bih  = (const float*)d_in[13];
    const float* bhh  = (const float*)d_in[14];
    const float* fc0w = (const float*)d_in[15];
    const float* fc0b = (const float*)d_in[16];
    const float* fc1w = (const float*)d_in[17];
    const float* fc1b = (const float*)d_in[18];
    const float* fc2w = (const float*)d_in[19];
    const float* fc2b = (const float*)d_in[20];
    const float* fc3w = (const float*)d_in[21];
    const float* fc3b = (const float*)d_in[22];

    float* wsf  = (float*)d_ws;
    float* y    = wsf + OFF_Y;
    float* z    = wsf + OFF_Z;
    float* gi   = wsf + OFF_GI;
    uint*  w16  = (uint*)(wsf + OFF_WHH);
    float* c12  = wsf + OFF_C12;
    float* dd   = wsf + OFF_DD;
    float* hend = wsf + OFF_HEND;
    float* out  = (float*)d_out;

    k_pack_prep<<<385, 256, 0, stream>>>(whh, w16, flw, flb, fa, c12, dd);
    k_conv<<<dim3(4, 64), 256, 0, stream>>>(x, cw, cb, y, z);
    k_feat<<<dim3(4, 64), 256, 0, stream>>>(y, c12, dd, fb, z);
    k_temp<<<dim3(4, 64), 512, 0, stream>>>(y, tlw, tlb, ta, tb, z);
    k_gi<<<dim3(6, 128), 256, 0, stream>>>(z, wih, bih, gi);
    k_gru<<<64, 512, 0, stream>>>(gi, w16, bhh, hend);
    k_fc<<<64, 256, 0, stream>>>(hend, fc0w, fc0b, fc1w, fc1b, fc2w, fc2b, fc3w, fc3b, out);
}